// Round 10
// baseline (151.996 us; speedup 1.0000x reference)
//
#include <hip/hip_runtime.h>
#include <cstdint>

// Problem constants
#define C_IN   128
#define C_OUT  256
#define KK     1152      // C_IN * 9 (im2col K)
#define NPIX   4096      // 64*64
#define BS     16
#define QMAXF  127.0f

typedef int v4i __attribute__((ext_vector_type(4)));

// ---- workspace layout (bytes) ---- compact (high-water 410 KB).
#define OFF_WPART 0          // 16*1152*4 = 73728
#define OFF_APART 73728      // 8*1152*4  = 36864 -> ends 110592
#define OFF_QW    110592     // 256*1152  = 294912 -> ends 405504
#define OFF_QMUL  405504     // 1152*4    = 4608  -> ends 410112
#define OFF_SCAL  410112     // 3*4
// w_part and qWp are disjoint: k_scalequant reads w_part while writing qWp.

// K-A: fused act_scale (blocks 0..1023) + w_scale (blocks 1024..1103).
__global__ void k_prep(const float* __restrict__ x, const float* __restrict__ wgt,
                       float* __restrict__ act_part, float* __restrict__ w_part) {
    const int tid = threadIdx.x;
    if (blockIdx.x >= 1024) {
        int t = blockIdx.x - 1024;        // 0..79
        int j = (t % 5) * 256 + tid;
        int s = t / 5;                    // 0..15
        if (j >= KK) return;
        const float* p = wgt + (size_t)s * 16 * KK + j;
        float m = 0.f;
#pragma unroll
        for (int i = 0; i < 16; i++) m = fmaxf(m, fabsf(p[(size_t)i * KK]));
        w_part[s * KK + j] = m;
        return;
    }
    const int c = blockIdx.x >> 3, s = blockIdx.x & 7;
    float m[9];
#pragma unroll
    for (int i = 0; i < 9; i++) m[i] = 0.f;
    const float4* xp4 = (const float4*)(x + (size_t)(s * 2) * (C_IN * NPIX) + (size_t)c * NPIX);
    const int img4 = C_IN * NPIX / 4;
    for (int v = tid; v < 2048; v += 256) {
        int half = v >> 10;
        int hw4  = v & 1023;
        int h   = hw4 >> 4;
        int w4i = hw4 & 15;
        float4 f = xp4[half * img4 + hw4];
        float ax = fabsf(f.x), ay = fabsf(f.y), az = fabsf(f.z), aw = fabsf(f.w);
        float vall = fmaxf(fmaxf(ax, ay), fmaxf(az, aw));
        float vnoF = (w4i == 0)  ? fmaxf(fmaxf(ay, az), aw) : vall;  // excl col 0
        float vnoL = (w4i == 15) ? fmaxf(fmaxf(ax, ay), az) : vall;  // excl col 63
        bool r0 = (h <= 62), r2 = (h >= 1);
        m[0] = fmaxf(m[0], r0 ? vnoL : 0.f);
        m[1] = fmaxf(m[1], r0 ? vall : 0.f);
        m[2] = fmaxf(m[2], r0 ? vnoF : 0.f);
        m[3] = fmaxf(m[3], vnoL);
        m[4] = fmaxf(m[4], vall);
        m[5] = fmaxf(m[5], vnoF);
        m[6] = fmaxf(m[6], r2 ? vnoL : 0.f);
        m[7] = fmaxf(m[7], r2 ? vall : 0.f);
        m[8] = fmaxf(m[8], r2 ? vnoF : 0.f);
    }
    __shared__ float sm[9][4];
    int lane = tid & 63, wid = tid >> 6;
#pragma unroll
    for (int i = 0; i < 9; i++) {
        float v = m[i];
        for (int off = 32; off > 0; off >>= 1) v = fmaxf(v, __shfl_down(v, off));
        if (lane == 0) sm[i][wid] = v;
    }
    __syncthreads();
    if (tid < 9) {
        float v = fmaxf(fmaxf(sm[tid][0], sm[tid][1]), fmaxf(sm[tid][2], sm[tid][3]));
        act_part[s * KK + c * 9 + tid] = v;
    }
}

// K-B2: FUSED scales + weight-quant (257 blocks x 256 thr).
__global__ void k_scalequant(const float* __restrict__ act_part, const float* __restrict__ w_part,
                             const float* __restrict__ wgt,
                             float* __restrict__ qmul, float* __restrict__ scalars,
                             signed char* __restrict__ qWp) {
    const int tid = threadIdx.x;
    __shared__ float ssc[KK];
    __shared__ float red[16];
    __shared__ float s_sw, s_sx;
    float mx = 0.f, mw = 0.f;
    for (int j = tid; j < KK; j += 256) {
        float a = 0.f;
#pragma unroll
        for (int s = 0; s < 8; s++) a = fmaxf(a, act_part[s * KK + j]);
        float wv = 0.f;
#pragma unroll
        for (int s = 0; s < 16; s++) wv = fmaxf(wv, w_part[s * KK + j]);
        float sc = sqrtf(a) / sqrtf(wv);
        if (sc == 0.f) sc = 1.0f;
        ssc[j] = sc;
        mx = fmaxf(mx, a / sc);
        mw = fmaxf(mw, wv * sc);
    }
    int lane = tid & 63, wid = tid >> 6;
    for (int off = 32; off > 0; off >>= 1) {
        mx = fmaxf(mx, __shfl_down(mx, off));
        mw = fmaxf(mw, __shfl_down(mw, off));
    }
    if (lane == 0) { red[wid] = mx; red[8 + wid] = mw; }
    __syncthreads();
    if (tid == 0) {
        float a = fmaxf(fmaxf(red[0], red[1]), fmaxf(red[2], red[3]));
        float b = fmaxf(fmaxf(red[8], red[9]), fmaxf(red[10], red[11]));
        float s_x = a / QMAXF; if (s_x == 0.f) s_x = 1.f;
        float s_w = b / QMAXF; if (s_w == 0.f) s_w = 1.f;
        s_sx = s_x; s_sw = s_w;
    }
    __syncthreads();
    const int bid = blockIdx.x;
    if (bid == 0) {
        const float s_x = s_sx, s_w = s_sw;
        if (tid == 0) { scalars[0] = s_x; scalars[1] = s_w; scalars[2] = s_x * s_w; }
        for (int j = tid; j < KK; j += 256) qmul[j] = 1.0f / (ssc[j] * s_x);
        return;
    }
    const int m = bid - 1;
    const float s_w = s_sw;
    for (int kp = tid; kp < KK; kp += 256) {
        int tap = kp >> 7, c = kp & 127;
        int j = c * 9 + tap;
        float t = wgt[(size_t)m * KK + j] * ssc[j];
        float q = rintf(t / s_w);
        q = fminf(fmaxf(q, -QMAXF), QMAXF);
        qWp[(size_t)m * KK + kp] = (signed char)(int)q;
    }
}

// K-D v7: PRODUCER-CONSUMER WAVE SPECIALIZATION (AITER pattern). 512 thr:
// waves 0-3 = producers (quantize+pack x rows -> Bs; hold xr/xrn, NO acc),
// waves 4-7 = consumers (LDS->MFMA; hold acc[4][4], NO xr). Disjoint if/else
// bodies -> live ranges don't overlap -> regs = max(~95,~105), under the
// (512,4) 128 cap (in-wave pipelining spilled twice: R2, R8).
// Phase ph: producers write Bs[ph&1] (tap ph); consumers MFMA tap ph-1 from
// Bs[(ph-1)&1]. One barrier/phase; last conflicting access 2 phases back.
// Each branch executes IDENTICAL barrier counts (11) - s_barrier is wave-counted.
// Bs layout/swizzle and all math identical to R9 (absmax must stay 0.03125).
__global__ __launch_bounds__(512, 4) void k_gemm(const signed char* __restrict__ qWp,
                                                 const float* __restrict__ x,
                                                 const float* __restrict__ qmul,
                                                 const float* __restrict__ scalars,
                                                 const float* __restrict__ bias,
                                                 float* __restrict__ out) {
    __shared__ __align__(16) signed char Bs[2][64 * 128];  // 2 x 8 KB
    __shared__ float qm[KK];                               // permuted qmul [tap][c]
    const int tid = threadIdx.x;
    const int lane = tid & 63, wv = tid >> 6;              // 8 waves
    const int bid = blockIdx.x;
    const int swz = (bid & 7) * 128 + (bid >> 3);          // bijective (1024 % 8 == 0)
    const int b  = swz >> 6;
    const int oh = swz & 63;
    const float* xb = x + (size_t)b * (C_IN * NPIX);

    for (int i = tid; i < KK; i += 512) {
        int tap = i >> 7, c = i & 127;
        qm[i] = qmul[c * 9 + tap];
    }

    if (wv < 4) {
        // ================= PRODUCER: 4 waves x 32 channels each ============
        const int c0 = wv * 32;
        float xr[32], xrn[32];
        {   // group 0 row (ih = oh-1, guarded zero-fill)
            const bool ok = oh >= 1;
            const float* sp = xb + (oh - 1) * 64 + lane;
#pragma unroll
            for (int d = 0; d < 32; d++) xr[d] = ok ? sp[(size_t)(c0 + d) * NPIX] : 0.f;
        }
        __syncthreads();   // [B0] qm ready

#pragma unroll
        for (int ph = 0; ph < 10; ph++) {
            if (ph < 9) {
                const int tap = ph;
                const int jj = tap - (tap / 3) * 3;
                const int s  = jj - 1;
                // rotate row buffer at group starts (xrn loaded >=3 phases ago)
                if (tap == 3 || tap == 6) {
#pragma unroll
                    for (int d = 0; d < 32; d++) xr[d] = xrn[d];
                }
                signed char* bsp = (signed char*)Bs[tap & 1];
                int n = lane - s;
                bool valid = (unsigned)n < 64u;
                int wrow = valid ? n : (s == -1 ? 0 : 63);   // edge lane -> zero row
#pragma unroll
                for (int ha = 0; ha < 2; ha++) {
                    const float* qmt = qm + tap * 128 + c0 + ha * 16;
                    const float* xv = xr + ha * 16;
                    int pk[4];
#pragma unroll
                    for (int d4 = 0; d4 < 4; d4++) {
                        int q0 = (int)rintf(xv[d4 * 4 + 0] * qmt[d4 * 4 + 0]);
                        int q1 = (int)rintf(xv[d4 * 4 + 1] * qmt[d4 * 4 + 1]);
                        int q2 = (int)rintf(xv[d4 * 4 + 2] * qmt[d4 * 4 + 2]);
                        int q3 = (int)rintf(xv[d4 * 4 + 3] * qmt[d4 * 4 + 3]);
                        unsigned t0 = __builtin_amdgcn_perm((unsigned)q1, (unsigned)q0, 0x0c0c0400u);
                        unsigned t1 = __builtin_amdgcn_perm((unsigned)q3, (unsigned)q2, 0x0c0c0400u);
                        int w = (int)__builtin_amdgcn_perm(t1, t0, 0x05040100u);
                        pk[d4] = valid ? w : 0;
                    }
                    *(v4i*)(bsp + wrow * 128 + (((wv * 2 + ha) ^ (wrow & 7)) * 16)) =
                        (v4i){pk[0], pk[1], pk[2], pk[3]};
                }
                // issue next group's row load (3-phase window before use)
                if (tap == 0) {
                    const float* sp = xb + oh * 64 + lane;   // ih = oh, always valid
#pragma unroll
                    for (int d = 0; d < 32; d++) xrn[d] = sp[(size_t)(c0 + d) * NPIX];
                }
                if (tap == 3) {
                    const bool ok = (oh + 1) < 64;
                    const float* sp = xb + (oh + 1) * 64 + lane;
#pragma unroll
                    for (int d = 0; d < 32; d++) xrn[d] = ok ? sp[(size_t)(c0 + d) * NPIX] : 0.f;
                }
            }
            __syncthreads();   // [B1..B10]
        }
        return;
    } else {
        // ================= CONSUMER: 4 waves x 64 M-rows each ==============
        const int cw = wv - 4;
        const signed char* aBase = qWp + (size_t)(cw * 64 + (lane & 15)) * KK + (lane >> 4) * 16;
        v4i acc[4][4];
#pragma unroll
        for (int i = 0; i < 4; i++)
#pragma unroll
            for (int jq = 0; jq < 4; jq++) acc[i][jq] = (v4i){0, 0, 0, 0};

        __syncthreads();   // [B0] qm ready

#pragma unroll
        for (int ph = 0; ph < 10; ph++) {
            if (ph > 0) {
                const int tap = ph - 1;
                const signed char* bsp = (const signed char*)Bs[tap & 1];
#pragma unroll
                for (int h = 0; h < 2; h++) {
                    // af loads per-h (16 regs, not 32): h=0 at phase start,
                    // h=1 issued under h=0's MFMAs (compiler hoists).
                    v4i afh[4];
#pragma unroll
                    for (int mt = 0; mt < 4; mt++)
                        afh[mt] = *(const v4i*)(aBase + (size_t)mt * 16 * KK + tap * 128 + h * 64);
                    const int q4 = h * 4 + (lane >> 4);
                    v4i bf[4];
#pragma unroll
                    for (int nt = 0; nt < 4; nt++) {
                        int rb = nt * 16 + (lane & 15);
                        bf[nt] = *(const v4i*)(bsp + rb * 128 + ((q4 ^ (rb & 7)) * 16));
                    }
#pragma unroll
                    for (int mt = 0; mt < 4; mt++)
#pragma unroll
                        for (int nt = 0; nt < 4; nt++)
                            acc[mt][nt] = __builtin_amdgcn_mfma_i32_16x16x64_i8(afh[mt], bf[nt], acc[mt][nt], 0, 0, 0);
                }
            }
            __syncthreads();   // [B1..B10]
        }

        const float ssp = scalars[2];
        const int quad = lane >> 4, col = lane & 15;
        float* obase = out + ((size_t)b * C_OUT) * NPIX + oh * 64;
#pragma unroll
        for (int mt = 0; mt < 4; mt++) {
            float bv[4];
#pragma unroll
            for (int rg = 0; rg < 4; rg++)
                bv[rg] = bias[cw * 64 + mt * 16 + quad * 4 + rg];
#pragma unroll
            for (int nt = 0; nt < 4; nt++) {
                int n = nt * 16 + col;
#pragma unroll
                for (int rg = 0; rg < 4; rg++) {
                    int m = cw * 64 + mt * 16 + quad * 4 + rg;   // c_out
                    obase[(size_t)m * NPIX + n] = (float)acc[mt][nt][rg] * ssp + bv[rg];
                }
            }
        }
    }
}

extern "C" void kernel_launch(void* const* d_in, const int* in_sizes, int n_in,
                              void* d_out, int out_size, void* d_ws, size_t ws_size,
                              hipStream_t stream) {
    const float* x    = (const float*)d_in[0];
    const float* wgt  = (const float*)d_in[1];
    const float* bias = (const float*)d_in[2];
    float* out = (float*)d_out;

    char* ws = (char*)d_ws;
    float* w_part    = (float*)(ws + OFF_WPART);
    float* act_part  = (float*)(ws + OFF_APART);
    signed char* qWp = (signed char*)(ws + OFF_QW);
    float* qmul      = (float*)(ws + OFF_QMUL);
    float* scalars   = (float*)(ws + OFF_SCAL);

    k_prep<<<1104, 256, 0, stream>>>(x, wgt, act_part, w_part);
    k_scalequant<<<257, 256, 0, stream>>>(act_part, w_part, wgt, qmul, scalars, qWp);
    k_gemm<<<BS * 64, 512, 0, stream>>>(qWp, x, qmul, scalars, bias, out);
}

// Round 11
// 142.184 us; speedup vs baseline: 1.0690x; 1.0690x over previous
//
#include <hip/hip_runtime.h>
#include <cstdint>

// Problem constants
#define C_IN   128
#define C_OUT  256
#define KK     1152      // C_IN * 9 (im2col K)
#define NPIX   4096      // 64*64
#define BS     16
#define QMAXF  127.0f

typedef int v4i __attribute__((ext_vector_type(4)));

// ---- workspace layout (bytes) ---- compact (high-water 410 KB).
#define OFF_WPART 0          // 16*1152*4 = 73728
#define OFF_APART 73728      // 8*1152*4  = 36864 -> ends 110592
#define OFF_QW    110592     // 256*1152  = 294912 -> ends 405504
#define OFF_QMUL  405504     // 1152*4    = 4608  -> ends 410112
#define OFF_SCAL  410112     // 3*4
// w_part and qWp are disjoint: k_scalequant reads w_part while writing qWp.

// K-A: fused act_scale (blocks 0..1023) + w_scale (blocks 1024..1103).
// Act: float4 loads; 3 col-class maxes per float4 + row-class predication.
__global__ void k_prep(const float* __restrict__ x, const float* __restrict__ wgt,
                       float* __restrict__ act_part, float* __restrict__ w_part) {
    const int tid = threadIdx.x;
    if (blockIdx.x >= 1024) {
        int t = blockIdx.x - 1024;        // 0..79
        int j = (t % 5) * 256 + tid;
        int s = t / 5;                    // 0..15
        if (j >= KK) return;
        const float* p = wgt + (size_t)s * 16 * KK + j;
        float m = 0.f;
#pragma unroll
        for (int i = 0; i < 16; i++) m = fmaxf(m, fabsf(p[(size_t)i * KK]));
        w_part[s * KK + j] = m;
        return;
    }
    const int c = blockIdx.x >> 3, s = blockIdx.x & 7;
    float m[9];
#pragma unroll
    for (int i = 0; i < 9; i++) m[i] = 0.f;
    const float4* xp4 = (const float4*)(x + (size_t)(s * 2) * (C_IN * NPIX) + (size_t)c * NPIX);
    const int img4 = C_IN * NPIX / 4;     // float4 stride between the 2 images
    for (int v = tid; v < 2048; v += 256) {
        int half = v >> 10;               // image 0/1 of this s-slice
        int hw4  = v & 1023;              // float4 index within 4096 pixels
        int h   = hw4 >> 4;               // 16 float4 per 64-pix row
        int w4i = hw4 & 15;               // f4 index within row
        float4 f = xp4[half * img4 + hw4];
        float ax = fabsf(f.x), ay = fabsf(f.y), az = fabsf(f.z), aw = fabsf(f.w);
        float vall = fmaxf(fmaxf(ax, ay), fmaxf(az, aw));
        float vnoF = (w4i == 0)  ? fmaxf(fmaxf(ay, az), aw) : vall;  // excl col 0
        float vnoL = (w4i == 15) ? fmaxf(fmaxf(ax, ay), az) : vall;  // excl col 63
        bool r0 = (h <= 62), r2 = (h >= 1);
        m[0] = fmaxf(m[0], r0 ? vnoL : 0.f);
        m[1] = fmaxf(m[1], r0 ? vall : 0.f);
        m[2] = fmaxf(m[2], r0 ? vnoF : 0.f);
        m[3] = fmaxf(m[3], vnoL);
        m[4] = fmaxf(m[4], vall);
        m[5] = fmaxf(m[5], vnoF);
        m[6] = fmaxf(m[6], r2 ? vnoL : 0.f);
        m[7] = fmaxf(m[7], r2 ? vall : 0.f);
        m[8] = fmaxf(m[8], r2 ? vnoF : 0.f);
    }
    __shared__ float sm[9][4];
    int lane = tid & 63, wid = tid >> 6;
#pragma unroll
    for (int i = 0; i < 9; i++) {
        float v = m[i];
        for (int off = 32; off > 0; off >>= 1) v = fmaxf(v, __shfl_down(v, off));
        if (lane == 0) sm[i][wid] = v;
    }
    __syncthreads();
    if (tid < 9) {
        float v = fmaxf(fmaxf(sm[tid][0], sm[tid][1]), fmaxf(sm[tid][2], sm[tid][3]));
        act_part[s * KK + c * 9 + tid] = v;
    }
}

// K-B2: FUSED scales + weight-quant (257 blocks x 256 thr). Every block
// redundantly computes the scale table from the L2-hot partials (bit-identical
// fp); block 0 writes qmul+scalars, blocks 1..256 quantize one W-row.
__global__ void k_scalequant(const float* __restrict__ act_part, const float* __restrict__ w_part,
                             const float* __restrict__ wgt,
                             float* __restrict__ qmul, float* __restrict__ scalars,
                             signed char* __restrict__ qWp) {
    const int tid = threadIdx.x;
    __shared__ float ssc[KK];
    __shared__ float red[16];
    __shared__ float s_sw, s_sx;
    float mx = 0.f, mw = 0.f;
    for (int j = tid; j < KK; j += 256) {
        float a = 0.f;
#pragma unroll
        for (int s = 0; s < 8; s++) a = fmaxf(a, act_part[s * KK + j]);
        float wv = 0.f;
#pragma unroll
        for (int s = 0; s < 16; s++) wv = fmaxf(wv, w_part[s * KK + j]);
        float sc = sqrtf(a) / sqrtf(wv);
        if (sc == 0.f) sc = 1.0f;
        ssc[j] = sc;
        mx = fmaxf(mx, a / sc);    // exact: max_r |cols[r,j]/sc| == fl(act/sc)
        mw = fmaxf(mw, wv * sc);   // exact: max_i |w2[i,j]*sc|  == fl(wsc*sc)
    }
    int lane = tid & 63, wid = tid >> 6;
    for (int off = 32; off > 0; off >>= 1) {
        mx = fmaxf(mx, __shfl_down(mx, off));
        mw = fmaxf(mw, __shfl_down(mw, off));
    }
    if (lane == 0) { red[wid] = mx; red[8 + wid] = mw; }
    __syncthreads();
    if (tid == 0) {
        float a = fmaxf(fmaxf(red[0], red[1]), fmaxf(red[2], red[3]));
        float b = fmaxf(fmaxf(red[8], red[9]), fmaxf(red[10], red[11]));
        float s_x = a / QMAXF; if (s_x == 0.f) s_x = 1.f;
        float s_w = b / QMAXF; if (s_w == 0.f) s_w = 1.f;
        s_sx = s_x; s_sw = s_w;
    }
    __syncthreads();
    const int bid = blockIdx.x;
    if (bid == 0) {
        const float s_x = s_sx, s_w = s_sw;
        if (tid == 0) { scalars[0] = s_x; scalars[1] = s_w; scalars[2] = s_x * s_w; }
        for (int j = tid; j < KK; j += 256) qmul[j] = 1.0f / (ssc[j] * s_x);
        return;
    }
    const int m = bid - 1;
    const float s_w = s_sw;
    for (int kp = tid; kp < KK; kp += 256) {
        int tap = kp >> 7, c = kp & 127;
        int j = c * 9 + tap;
        float t = wgt[(size_t)m * KK + j] * ssc[j];
        float q = rintf(t / s_w);
        q = fminf(fmaxf(q, -QMAXF), QMAXF);
        qWp[(size_t)m * KK + kp] = (signed char)(int)q;
    }
}

// K-D: FUSED quant+GEMM — R3/R6/R9 schedule (best measured: 52.4-53.7 us over
// 8 structural variants; every deviation was neutral-to-worse, three spilled).
// Block = 256(M) x 64(N = 1 out row), 512 thr, 8 waves, acc[2][4]. x rows
// loaded ONCE per kh-group (prefetched a group ahead); kw shift via ds_write
// ROW address. Bs double-buffered, XOR 16B-chunk swizzle, ONE barrier per tap.
// A-fragments global->VGPR (L2-hot), prefetched one tap ahead. XCD swizzle
// (R3: FETCH 55->20 MB). perm-pack produce (R4: VALU 27->23%). No clamp in
// produce (s_x construction bounds rintf to [-127,127]).
// DO NOT add setprio / deeper pipelining / wave specialization: R2/R8/R10 all
// regressed via regalloc perturbation at the (512,4) 128-reg cliff.
// Spill tripwire = WRITE_SIZE > 66 MB (VGPR_Count=64 in trace is unreliable).
__global__ __launch_bounds__(512, 4) void k_gemm(const signed char* __restrict__ qWp,
                                                 const float* __restrict__ x,
                                                 const float* __restrict__ qmul,
                                                 const float* __restrict__ scalars,
                                                 const float* __restrict__ bias,
                                                 float* __restrict__ out) {
    __shared__ __align__(16) signed char Bs[2][64 * 128];  // 2 x 8 KB
    __shared__ float qm[KK];                               // permuted qmul [tap][c]
    const int tid = threadIdx.x;
    const int lane = tid & 63, wv = tid >> 6;              // 8 waves
    const int bid = blockIdx.x;
    const int swz = (bid & 7) * 128 + (bid >> 3);          // bijective (1024 % 8 == 0)
    const int b  = swz >> 6;
    const int oh = swz & 63;
    const float* xb = x + (size_t)b * (C_IN * NPIX);
    const int c0 = wv * 16;                                // thread's channel chunk

    for (int i = tid; i < KK; i += 512) {
        int tap = i >> 7, c = i & 127;
        qm[i] = qmul[c * 9 + tap];
    }

    // A addressing: row = wv*32 + mt*16 + (lane&15); 16B chunk (lane>>4) of K=64 half h
    const signed char* aBase = qWp + (size_t)(wv * 32 + (lane & 15)) * KK + (lane >> 4) * 16;

    v4i acc[2][4];
#pragma unroll
    for (int i = 0; i < 2; i++)
#pragma unroll
        for (int jq = 0; jq < 4; jq++) acc[i][jq] = (v4i){0, 0, 0, 0};

    // preload: x row for kh-group 0 (ih = oh-1, guarded zero-fill), A frags tap 0
    float xr[16], xrn[16];
    {
        const bool ok = oh >= 1;
        const float* s = xb + (oh - 1) * 64 + lane;
#pragma unroll
        for (int d = 0; d < 16; d++) xr[d] = ok ? s[(size_t)(c0 + d) * NPIX] : 0.f;
    }
    v4i af[2][2], afn[2][2];
#pragma unroll
    for (int h = 0; h < 2; h++)
#pragma unroll
        for (int mt = 0; mt < 2; mt++)
            af[h][mt] = *(const v4i*)(aBase + (size_t)mt * 16 * KK + 0 * 128 + h * 64);

    __syncthreads();   // qm ready

#pragma unroll
    for (int tap = 0; tap < 9; tap++) {
        const int g  = (tap * 11) >> 5;      // kh = tap/3
        const int jj = tap - g * 3;          // kw
        const int s  = jj - 1;               // horizontal shift -1/0/+1
        signed char* bsp = (signed char*)Bs[tap & 1];

        // ---- produce Bs(tap): thread's value belongs to output pixel n = lane - s.
        {
            int n = lane - s;
            bool valid = (unsigned)n < 64u;
            int wrow = valid ? n : (s == -1 ? 0 : 63);   // edge lane fills the zero row
            const float* qmt = qm + tap * 128 + c0;
            int pk[4];
#pragma unroll
            for (int d4 = 0; d4 < 4; d4++) {
                int q0 = (int)rintf(xr[d4 * 4 + 0] * qmt[d4 * 4 + 0]);
                int q1 = (int)rintf(xr[d4 * 4 + 1] * qmt[d4 * 4 + 1]);
                int q2 = (int)rintf(xr[d4 * 4 + 2] * qmt[d4 * 4 + 2]);
                int q3 = (int)rintf(xr[d4 * 4 + 3] * qmt[d4 * 4 + 3]);
                unsigned t0 = __builtin_amdgcn_perm((unsigned)q1, (unsigned)q0, 0x0c0c0400u);
                unsigned t1 = __builtin_amdgcn_perm((unsigned)q3, (unsigned)q2, 0x0c0c0400u);
                int w = (int)__builtin_amdgcn_perm(t1, t0, 0x05040100u);
                pk[d4] = valid ? w : 0;
            }
            *(v4i*)(bsp + wrow * 128 + ((wv ^ (wrow & 7)) * 16)) = (v4i){pk[0], pk[1], pk[2], pk[3]};
        }

        // ---- prefetch next kh-group's x row (issued once per group, ~3-tap window) ----
        if (jj == 0 && g < 2) {
            const bool ok = (unsigned)(oh + g) < 64u;
            const float* sp = xb + (oh + g) * 64 + lane;
#pragma unroll
            for (int d = 0; d < 16; d++) xrn[d] = ok ? sp[(size_t)(c0 + d) * NPIX] : 0.f;
        }

        __syncthreads();   // Bs(tap) ready; dbuf covers WAR vs tap-2 reads

        // ---- prefetch A fragments for tap+1 (hidden behind MFMA + next produce) ----
        if (tap < 8) {
#pragma unroll
            for (int h = 0; h < 2; h++)
#pragma unroll
                for (int mt = 0; mt < 2; mt++)
                    afn[h][mt] = *(const v4i*)(aBase + (size_t)mt * 16 * KK + (tap + 1) * 128 + h * 64);
        }

        // ---- MFMA: two K=64 substeps ----
#pragma unroll
        for (int h = 0; h < 2; h++) {
            const int q4 = h * 4 + (lane >> 4);
            v4i bf[4];
#pragma unroll
            for (int nt = 0; nt < 4; nt++) {
                int rb = nt * 16 + (lane & 15);
                bf[nt] = *(const v4i*)(bsp + rb * 128 + ((q4 ^ (rb & 7)) * 16));
            }
#pragma unroll
            for (int mt = 0; mt < 2; mt++)
#pragma unroll
                for (int nt = 0; nt < 4; nt++)
                    acc[mt][nt] = __builtin_amdgcn_mfma_i32_16x16x64_i8(af[h][mt], bf[nt], acc[mt][nt], 0, 0, 0);
        }

        // rotate prefetch regs (renamed under full unroll)
        if (tap < 8) {
#pragma unroll
            for (int h = 0; h < 2; h++)
#pragma unroll
                for (int mt = 0; mt < 2; mt++) af[h][mt] = afn[h][mt];
        }
        if (jj == 2 && g < 2) {
#pragma unroll
            for (int d = 0; d < 16; d++) xr[d] = xrn[d];
        }
    }

    const float ssp = scalars[2];
    const int quad = lane >> 4, col = lane & 15;
    float bv[2][4];
#pragma unroll
    for (int mt = 0; mt < 2; mt++)
#pragma unroll
        for (int rg = 0; rg < 4; rg++)
            bv[mt][rg] = bias[wv * 32 + mt * 16 + quad * 4 + rg];

    float* obase = out + ((size_t)b * C_OUT) * NPIX + oh * 64;
#pragma unroll
    for (int mt = 0; mt < 2; mt++) {
#pragma unroll
        for (int nt = 0; nt < 4; nt++) {
            int n = nt * 16 + col;
#pragma unroll
            for (int rg = 0; rg < 4; rg++) {
                int m = wv * 32 + mt * 16 + quad * 4 + rg;   // c_out
                obase[(size_t)m * NPIX + n] = (float)acc[mt][nt][rg] * ssp + bv[mt][rg];
            }
        }
    }
}

extern "C" void kernel_launch(void* const* d_in, const int* in_sizes, int n_in,
                              void* d_out, int out_size, void* d_ws, size_t ws_size,
                              hipStream_t stream) {
    const float* x    = (const float*)d_in[0];
    const float* wgt  = (const float*)d_in[1];
    const float* bias = (const float*)d_in[2];
    float* out = (float*)d_out;

    char* ws = (char*)d_ws;
    float* w_part    = (float*)(ws + OFF_WPART);
    float* act_part  = (float*)(ws + OFF_APART);
    signed char* qWp = (signed char*)(ws + OFF_QW);
    float* qmul      = (float*)(ws + OFF_QMUL);
    float* scalars   = (float*)(ws + OFF_SCAL);

    k_prep<<<1104, 256, 0, stream>>>(x, wgt, act_part, w_part);
    k_scalequant<<<257, 256, 0, stream>>>(act_part, w_part, wgt, qmul, scalars, qWp);
    k_gemm<<<BS * 64, 512, 0, stream>>>(qWp, x, qmul, scalars, bias, out);
}